// Round 14
// baseline (117.159 us; speedup 1.0000x reference)
//
#include <hip/hip_runtime.h>
#include <hip/hip_bf16.h>
#include <math.h>

typedef short short8 __attribute__((ext_vector_type(8)));
typedef float f32x16 __attribute__((ext_vector_type(16)));

#define BB 16
#define CC 256
#define HH 64
#define WW 64
#define HWX 4096
#define DD 4
#define KD 9
#define KK 81
#define GR 4
#define NSLOT 12

// LDS visibility barrier WITHOUT vmcnt drain (global loads/stores stay in flight)
#define RAW_BAR() do { \
    asm volatile("s_waitcnt lgkmcnt(0)" ::: "memory"); \
    __builtin_amdgcn_s_barrier(); \
} while (0)

__device__ __forceinline__ short bf16c(float x) {
    __hip_bfloat16 h = __float2bfloat16(x);
    return *reinterpret_cast<short*>(&h);
}

// 512B-row layout, 5-bit XOR swizzle (R11-measured: 0 conflicts)
__device__ __forceinline__ int lds_byte(int w, int c) {
    return (w * 512 + c * 2) ^ ((w & 31) << 4);
}

// 16 strided loads: c = c0..c0+15 at w=l (row, c0 wave-uniform)
__device__ __forceinline__ void b_issue16(const float* __restrict__ row,
                                          int c0, int l, float* v) {
    #pragma unroll
    for (int j = 0; j < 16; ++j)
        v[j] = row[(size_t)(c0 + j) * HWX + l];
}

// cvt + 2 swizzled ds_write_b128; returns sumsq partial
__device__ __forceinline__ float b_commit16(const float* v, unsigned short* bufp,
                                            int c0, int l) {
    float ss = 0.f;
    #pragma unroll
    for (int j = 0; j < 16; ++j) ss += v[j] * v[j];
    #pragma unroll
    for (int h = 0; h < 2; ++h) {
        short8 st;
        #pragma unroll
        for (int j = 0; j < 8; ++j) st[j] = bf16c(v[h * 8 + j]);
        *(short8*)((char*)bufp + lds_byte(l, c0 + h * 8)) = st;
    }
    return ss;
}

// (512,2): an 8-wave block physically occupies 2 waves/SIMD, so this min-waves
// value clamps nothing -- it only raises the VGPR allocator cap 128 -> 256.
__global__ __launch_bounds__(512, 2) void corr_mfma(
    const float* __restrict__ fA, const float* __restrict__ fB,
    float* __restrict__ out)
{
    __shared__ __attribute__((aligned(16))) unsigned short buf[2][WW * CC]; // 64 KB
    __shared__ float part[2][8 * WW];   // 4 KB ([1] aliases A partials)
    __shared__ float invA_ls[GR][WW];   // 1 KB

    const int bid = blockIdx.x;                       // 256 blocks = 1/CU
    const int swzb = (bid & 7) * 32 + (bid >> 3);     // XCD-bijective (256%8==0)
    const int b = swzb >> 4, jr = swzb & 15;
    const int h0 = 4 * jr;

    const int tid = threadIdx.x;
    const int l = tid & 63;
    const int wvu = __builtin_amdgcn_readfirstlane(tid >> 6);  // wave id -> SGPR
    const int g = wvu >> 1;               // group: row h0+g (0..3)
    const int tj = wvu & 1;               // B n-half
    const int hg = h0 + g;
    const int ml = l & 31, kg = l >> 5;
    const int n = tj * 32 + ml;           // B row (w')

    // ---- A prologue: 4 rows staged through buf in 2 rounds ----
    short8 afrL[16], afrH[16];            // m-half 0 / 1 fragments (128 VGPR)
    #pragma unroll
    for (int t = 0; t < 2; ++t) {
        {   // stage: wave role (rs, cq) independent of compute role
            const int rs = wvu >> 2;                  // row within round (uniform)
            const int cq = wvu & 3;                   // c-quarter (uniform)
            const float* Ar = fA + (size_t)b * CC * HWX + (h0 + 2 * t + rs) * WW;
            float ss = 0.f;
            #pragma unroll
            for (int r = 0; r < 8; ++r) {
                const int c = cq * 64 + r * 8;        // uniform
                float v[8]; short8 st;
                #pragma unroll
                for (int j = 0; j < 8; ++j) v[j] = Ar[(size_t)(c + j) * HWX + l];
                #pragma unroll
                for (int j = 0; j < 8; ++j) ss += v[j] * v[j];
                #pragma unroll
                for (int j = 0; j < 8; ++j) st[j] = bf16c(v[j]);
                *(short8*)((char*)buf[rs] + lds_byte(l, c)) = st;
            }
            part[1][wvu * 64 + l] = ss;
        }
        __syncthreads();                              // A rows 2t,2t+1 staged
        if (tid < 2 * WW) {                           // invA for rows 2t, 2t+1
            const int rs = tid >> 6, ll = tid & 63;
            float s = part[1][(rs * 4 + 0) * 64 + ll] + part[1][(rs * 4 + 1) * 64 + ll]
                    + part[1][(rs * 4 + 2) * 64 + ll] + part[1][(rs * 4 + 3) * 64 + ll];
            invA_ls[2 * t + rs][ll] = 1.f / fmaxf(sqrtf(s), 1e-12f);
        }
        if ((g >> 1) == t) {                          // hoist both m-halves
            #pragma unroll
            for (int s = 0; s < 16; ++s) {
                afrL[s] = *(const short8*)((const char*)buf[g & 1] + lds_byte(ml,      s * 16 + kg * 8));
                afrH[s] = *(const short8*)((const char*)buf[g & 1] + lds_byte(32 + ml, s * 16 + kg * 8));
            }
        }
        __syncthreads();                              // hoist reads + invA visible
        if ((g >> 1) == t) {                          // fold invA (register-only)
            const float ia0 = invA_ls[g][ml], ia1 = invA_ls[g][32 + ml];
            #pragma unroll
            for (int s = 0; s < 16; ++s) {
                short8 t0 = afrL[s], t1 = afrH[s];
                #pragma unroll
                for (int j = 0; j < 8; ++j) {
                    union { unsigned u; float f; } u0, u1;
                    u0.u = ((unsigned)(unsigned short)t0[j]) << 16;
                    u1.u = ((unsigned)(unsigned short)t1[j]) << 16;
                    t0[j] = bf16c(u0.f * ia0);
                    t1[j] = bf16c(u1.f * ia1);
                }
                afrL[s] = t0; afrH[s] = t1;
            }
        }
    }

    // ---- B slot 0 staging ----
    const float* fBb = fB + (size_t)b * CC * HWX;
    {
        const int hb0 = h0 - DD;
        if ((unsigned)hb0 < HH) {
            const float* row = fBb + (size_t)hb0 * WW;
            float v[16];
            b_issue16(row, wvu * 32, l, v);
            float ss = b_commit16(v, buf[0], wvu * 32, l);
            b_issue16(row, wvu * 32 + 16, l, v);
            ss += b_commit16(v, buf[0], wvu * 32 + 16, l);
            part[0][wvu * 64 + l] = ss;
        }
    }
    __syncthreads();                                   // slot 0 ready

    // ---- slot loop: 12 slots serve 4 rows; B-frag read once, dual MFMA ----
    for (int r = 0; r < NSLOT; ++r) {
        const int cur = r & 1;
        const int hb = h0 - DD + r;
        const bool vcur = (unsigned)hb < HH;
        const bool vnext = (r + 1 < NSLOT) && ((unsigned)(hb + 1) < HH);
        const int dy = r - g;
        const bool dyv = (dy >= 0 && dy < KD);
        const bool comp = dyv && vcur;
        const float* nrow = fBb + (size_t)(hb + 1) * WW;
        float* ob = out + (((size_t)b * KK + dy * KD) * HH + hg) * WW;

        // 1. issue half0 of next row
        float v[16];
        if (vnext) b_issue16(nrow, wvu * 32, l, v);

        // 2. MFMA octet 1 (dual chain: one B-frag feeds both m-halves)
        f32x16 acc0, acc1;
        if (comp) {
            #pragma unroll
            for (int i = 0; i < 16; ++i) { acc0[i] = 0.f; acc1[i] = 0.f; }
            __builtin_amdgcn_s_setprio(1);
            #pragma unroll
            for (int s = 0; s < 8; ++s) {
                short8 bfr = *(const short8*)((const char*)buf[cur] + lds_byte(n, s * 16 + kg * 8));
                acc0 = __builtin_amdgcn_mfma_f32_32x32x16_bf16(afrL[s], bfr, acc0, 0, 0, 0);
                acc1 = __builtin_amdgcn_mfma_f32_32x32x16_bf16(afrH[s], bfr, acc1, 0, 0, 0);
            }
            __builtin_amdgcn_s_setprio(0);
        }

        // 3. commit half0, issue half1
        float ssn = 0.f;
        if (vnext) {
            ssn = b_commit16(v, buf[cur ^ 1], wvu * 32, l);
            b_issue16(nrow, wvu * 32 + 16, l, v);
        }

        // 4. MFMA octet 2 + direct banded store (both m-halves)
        if (comp) {
            __builtin_amdgcn_s_setprio(1);
            #pragma unroll
            for (int s = 8; s < 16; ++s) {
                short8 bfr = *(const short8*)((const char*)buf[cur] + lds_byte(n, s * 16 + kg * 8));
                acc0 = __builtin_amdgcn_mfma_f32_32x32x16_bf16(afrL[s], bfr, acc0, 0, 0, 0);
                acc1 = __builtin_amdgcn_mfma_f32_32x32x16_bf16(afrH[s], bfr, acc1, 0, 0, 0);
            }
            __builtin_amdgcn_s_setprio(0);
            float sB = 0.f;
            #pragma unroll
            for (int qq = 0; qq < 8; ++qq) sB += part[cur][qq * 64 + n];
            const float ibn = 1.f / fmaxf(sqrtf(sB), 1e-12f);
            #pragma unroll
            for (int rr = 0; rr < 16; ++rr) {
                // D layout (m74/m101): col = lane&31 (=w'), row = (rr&3)+8*(rr>>2)+4*kg
                const int wf = (rr & 3) + 8 * (rr >> 2) + 4 * kg;
                const int dx0 = n - wf + 4;            // m-half 0: w = wf
                if (dx0 >= 0 && dx0 < KD)
                    ob[(size_t)dx0 * HWX + wf] = acc0[rr] * ibn;
                const int dx1 = dx0 - 32;              // m-half 1: w = 32 + wf
                if (dx1 >= 0 && dx1 < KD)
                    ob[(size_t)dx1 * HWX + 32 + wf] = acc1[rr] * ibn;
            }
            if (tj == 1) {     // zero the 20 pad-corner entries of this plane
                int i = -1;
                if (l < 10) i = l;
                else if (l >= 16 && l < 26) i = l - 16;
                if (i >= 0) {
                    const int wz0 = (i < 4) ? 0 : (i < 7) ? 1 : (i < 9) ? 2 : 3;
                    const int dx0 = i - ((wz0 == 0) ? 0 : (wz0 == 1) ? 4 : (wz0 == 2) ? 7 : 9);
                    const int wz = (l < 10) ? wz0 : 63 - wz0;
                    const int dxz = (l < 10) ? dx0 : 8 - dx0;
                    ob[(size_t)dxz * HWX + wz] = 0.f;
                }
            }
        } else if (dyv) {
            // whole dy-plane is zero padding; out is poisoned so must write
            for (int i = tj * 64 + l; i < KD * WW; i += 128)
                ob[(size_t)(i >> 6) * HWX + (i & 63)] = 0.f;
        }

        // 5. commit half1, publish sumsq partial
        if (vnext) {
            ssn += b_commit16(v, buf[cur ^ 1], wvu * 32 + 16, l);
            part[cur ^ 1][wvu * 64 + l] = ssn;
        }
        RAW_BAR();
    }
}

extern "C" void kernel_launch(void* const* d_in, const int* in_sizes, int n_in,
                              void* d_out, int out_size, void* d_ws, size_t ws_size,
                              hipStream_t stream) {
    const float* fA = (const float*)d_in[0];
    const float* fB = (const float*)d_in[1];
    float* outp = (float*)d_out;
    corr_mfma<<<dim3(BB * HH / GR), 512, 0, stream>>>(fA, fB, outp);
}

// Round 15
// 82.046 us; speedup vs baseline: 1.4280x; 1.4280x over previous
//
#include <hip/hip_runtime.h>
#include <hip/hip_bf16.h>
#include <math.h>

typedef short short8 __attribute__((ext_vector_type(8)));
typedef float f32x16 __attribute__((ext_vector_type(16)));

#define BB 16
#define CC 256
#define HH 64
#define WW 64
#define HWX 4096
#define DD 4
#define KD 9
#define KK 81
#define NSLOT 10

// LDS visibility barrier WITHOUT vmcnt drain (global loads/stores stay in flight)
#define RAW_BAR() do { \
    asm volatile("s_waitcnt lgkmcnt(0)" ::: "memory"); \
    __builtin_amdgcn_s_barrier(); \
} while (0)

__device__ __forceinline__ short bf16c(float x) {
    __hip_bfloat16 h = __float2bfloat16(x);
    return *reinterpret_cast<short*>(&h);
}

// 512B-row layout, 5-bit XOR swizzle (R11-measured: 0 conflicts)
__device__ __forceinline__ int lds_byte(int w, int c) {
    return (w * 512 + c * 2) ^ ((w & 31) << 4);
}

// 16 strided loads: c = c0..c0+15 at w=l (row, c0 wave-uniform)
__device__ __forceinline__ void b_issue16(const float* __restrict__ row,
                                          int c0, int l, float* v) {
    #pragma unroll
    for (int j = 0; j < 16; ++j)
        v[j] = row[(size_t)(c0 + j) * HWX + l];
}

// cvt + 2 swizzled ds_write_b128; returns sumsq partial
__device__ __forceinline__ float b_commit16(const float* v, unsigned short* bufp,
                                            int c0, int l) {
    float ss = 0.f;
    #pragma unroll
    for (int j = 0; j < 16; ++j) ss += v[j] * v[j];
    #pragma unroll
    for (int h = 0; h < 2; ++h) {
        short8 st;
        #pragma unroll
        for (int j = 0; j < 8; ++j) st[j] = bf16c(v[h * 8 + j]);
        *(short8*)((char*)bufp + lds_byte(l, c0 + h * 8)) = st;
    }
    return ss;
}

// 256 threads = 4 waves = 1 wave/SIMD minimum -> allocator VGPR cap is 512,
// not 128 (the 512-thread path hard-caps at 128 and spilled, R12/R13).
__global__ __launch_bounds__(256) void corr_mfma(
    const float* __restrict__ fA, const float* __restrict__ fB,
    float* __restrict__ out)
{
    __shared__ __attribute__((aligned(16))) unsigned short buf[2][WW * CC]; // 64 KB
    __shared__ float part[2][4 * WW];   // 2 KB ([1] aliases A partials)
    __shared__ float invA_ls[2][WW];    // 0.5 KB

    const int bid = blockIdx.x;                       // 512 blocks
    const int swzb = (bid & 7) * 64 + (bid >> 3);     // XCD-bijective (512%8==0)
    const int b = swzb >> 5, jr = swzb & 31;
    const int h0 = 2 * jr;

    const int tid = threadIdx.x;
    const int l = tid & 63;
    const int wvu = __builtin_amdgcn_readfirstlane(tid >> 6);  // wave id -> SGPR
    const int g = wvu >> 1;               // row h0+g (0/1)     (uniform)
    const int tj = wvu & 1;               // B n-half           (uniform)
    const int hg = h0 + g;
    const int ml = l & 31, kg = l >> 5;
    const int n = tj * 32 + ml;           // B row (w')

    // ---- A prologue: wave (g,tj) stages c-half tj of row g into buf[g] ----
    const float* Abase = fA + (size_t)b * CC * HWX + hg * WW;
    {
        float ss = 0.f;
        #pragma unroll
        for (int r = 0; r < 16; ++r) {
            const int c = tj * 128 + r * 8;            // uniform
            float v[8]; short8 st;
            #pragma unroll
            for (int j = 0; j < 8; ++j) v[j] = Abase[(size_t)(c + j) * HWX + l];
            #pragma unroll
            for (int j = 0; j < 8; ++j) ss += v[j] * v[j];
            #pragma unroll
            for (int j = 0; j < 8; ++j) st[j] = bf16c(v[j]);
            *(short8*)((char*)buf[g] + lds_byte(l, c)) = st;
        }
        part[1][wvu * 64 + l] = ss;
    }
    __syncthreads();                                   // bar1: A staged
    if (tid < 2 * WW) {                                // invA rows 0,1
        const int rs = tid >> 6, ll = tid & 63;
        float s = part[1][(2 * rs) * 64 + ll] + part[1][(2 * rs + 1) * 64 + ll];
        invA_ls[rs][ll] = 1.f / fmaxf(sqrtf(s), 1e-12f);
    }
    short8 afrL[16], afrH[16];            // dual-M fragments (128 VGPR)
    #pragma unroll
    for (int s = 0; s < 16; ++s) {
        afrL[s] = *(const short8*)((const char*)buf[g] + lds_byte(ml,      s * 16 + kg * 8));
        afrH[s] = *(const short8*)((const char*)buf[g] + lds_byte(32 + ml, s * 16 + kg * 8));
    }
    __syncthreads();                                   // bar2: invA visible, hoist done
    {   // fold invA into A fragments (register-only)
        const float ia0 = invA_ls[g][ml], ia1 = invA_ls[g][32 + ml];
        #pragma unroll
        for (int s = 0; s < 16; ++s) {
            short8 t0 = afrL[s], t1 = afrH[s];
            #pragma unroll
            for (int j = 0; j < 8; ++j) {
                union { unsigned u; float f; } u0, u1;
                u0.u = ((unsigned)(unsigned short)t0[j]) << 16;
                u1.u = ((unsigned)(unsigned short)t1[j]) << 16;
                t0[j] = bf16c(u0.f * ia0);
                t1[j] = bf16c(u1.f * ia1);
            }
            afrL[s] = t0; afrH[s] = t1;
        }
    }

    // ---- B slot 0 staging: wave stages c in [wvu*64, wvu*64+64) ----
    const float* fBb = fB + (size_t)b * CC * HWX;
    {
        const int hb0 = h0 - DD;
        if ((unsigned)hb0 < HH) {
            const float* row = fBb + (size_t)hb0 * WW;
            float v[16];
            float ss = 0.f;
            #pragma unroll
            for (int ch = 0; ch < 4; ++ch) {
                b_issue16(row, wvu * 64 + ch * 16, l, v);
                ss += b_commit16(v, buf[0], wvu * 64 + ch * 16, l);
            }
            part[0][wvu * 64 + l] = ss;
        }
    }
    __syncthreads();                                   // slot 0 ready

    // ---- slot loop: 10 slots serve 2 rows; B-frag read once, dual MFMA ----
    for (int r = 0; r < NSLOT; ++r) {
        const int cur = r & 1;
        const int hb = h0 - DD + r;
        const bool vcur = (unsigned)hb < HH;
        const bool vnext = (r + 1 < NSLOT) && ((unsigned)(hb + 1) < HH);
        const int dy = r - g;
        const bool dyv = (dy >= 0 && dy < KD);
        const bool comp = dyv && vcur;
        const float* nrow = fBb + (size_t)(hb + 1) * WW;
        float* ob = out + (((size_t)b * KK + dy * KD) * HH + hg) * WW;

        // 1. issue first 32 loads of next row
        float va[16], vb[16];
        if (vnext) {
            b_issue16(nrow, wvu * 64, l, va);
            b_issue16(nrow, wvu * 64 + 16, l, vb);
        }

        // 2. MFMA octet 1 (one B-frag feeds both m-halves)
        f32x16 acc0, acc1;
        if (comp) {
            #pragma unroll
            for (int i = 0; i < 16; ++i) { acc0[i] = 0.f; acc1[i] = 0.f; }
            __builtin_amdgcn_s_setprio(1);
            #pragma unroll
            for (int s = 0; s < 8; ++s) {
                short8 bfr = *(const short8*)((const char*)buf[cur] + lds_byte(n, s * 16 + kg * 8));
                acc0 = __builtin_amdgcn_mfma_f32_32x32x16_bf16(afrL[s], bfr, acc0, 0, 0, 0);
                acc1 = __builtin_amdgcn_mfma_f32_32x32x16_bf16(afrH[s], bfr, acc1, 0, 0, 0);
            }
            __builtin_amdgcn_s_setprio(0);
        }

        // 3. commit first 32, issue last 32
        float ssn = 0.f;
        if (vnext) {
            ssn  = b_commit16(va, buf[cur ^ 1], wvu * 64, l);
            b_issue16(nrow, wvu * 64 + 32, l, va);
            ssn += b_commit16(vb, buf[cur ^ 1], wvu * 64 + 16, l);
            b_issue16(nrow, wvu * 64 + 48, l, vb);
        }

        // 4. MFMA octet 2 + direct banded store (both m-halves)
        if (comp) {
            __builtin_amdgcn_s_setprio(1);
            #pragma unroll
            for (int s = 8; s < 16; ++s) {
                short8 bfr = *(const short8*)((const char*)buf[cur] + lds_byte(n, s * 16 + kg * 8));
                acc0 = __builtin_amdgcn_mfma_f32_32x32x16_bf16(afrL[s], bfr, acc0, 0, 0, 0);
                acc1 = __builtin_amdgcn_mfma_f32_32x32x16_bf16(afrH[s], bfr, acc1, 0, 0, 0);
            }
            __builtin_amdgcn_s_setprio(0);
            float sB = part[cur][0 * 64 + n] + part[cur][1 * 64 + n]
                     + part[cur][2 * 64 + n] + part[cur][3 * 64 + n];
            const float ibn = 1.f / fmaxf(sqrtf(sB), 1e-12f);
            #pragma unroll
            for (int rr = 0; rr < 16; ++rr) {
                // D layout (m74/m101): col = lane&31 (=w'), row = (rr&3)+8*(rr>>2)+4*kg
                const int wf = (rr & 3) + 8 * (rr >> 2) + 4 * kg;
                const int dx0 = n - wf + 4;            // m-half 0: w = wf
                if (dx0 >= 0 && dx0 < KD)
                    ob[(size_t)dx0 * HWX + wf] = acc0[rr] * ibn;
                const int dx1 = dx0 - 32;              // m-half 1: w = 32 + wf
                if (dx1 >= 0 && dx1 < KD)
                    ob[(size_t)dx1 * HWX + 32 + wf] = acc1[rr] * ibn;
            }
            if (tj == 1) {     // zero the 20 pad-corner entries of this plane
                int i = -1;
                if (l < 10) i = l;
                else if (l >= 16 && l < 26) i = l - 16;
                if (i >= 0) {
                    const int wz0 = (i < 4) ? 0 : (i < 7) ? 1 : (i < 9) ? 2 : 3;
                    const int dxc = i - ((wz0 == 0) ? 0 : (wz0 == 1) ? 4 : (wz0 == 2) ? 7 : 9);
                    const int wz = (l < 10) ? wz0 : 63 - wz0;
                    const int dxz = (l < 10) ? dxc : 8 - dxc;
                    ob[(size_t)dxz * HWX + wz] = 0.f;
                }
            }
        } else if (dyv) {
            // whole dy-plane is zero padding; out is poisoned so must write
            for (int i = tj * 64 + l; i < KD * WW; i += 128)
                ob[(size_t)(i >> 6) * HWX + (i & 63)] = 0.f;
        }

        // 5. commit last 32, publish sumsq partial
        if (vnext) {
            ssn += b_commit16(va, buf[cur ^ 1], wvu * 64 + 32, l);
            ssn += b_commit16(vb, buf[cur ^ 1], wvu * 64 + 48, l);
            part[cur ^ 1][wvu * 64 + l] = ssn;
        }
        RAW_BAR();
    }
}

extern "C" void kernel_launch(void* const* d_in, const int* in_sizes, int n_in,
                              void* d_out, int out_size, void* d_ws, size_t ws_size,
                              hipStream_t stream) {
    const float* fA = (const float*)d_in[0];
    const float* fB = (const float*)d_in[1];
    float* outp = (float*)d_out;
    corr_mfma<<<dim3(BB * HH / 2), 256, 0, stream>>>(fA, fB, outp);
}

// Round 16
// 65.919 us; speedup vs baseline: 1.7773x; 1.2446x over previous
//
#include <hip/hip_runtime.h>
#include <hip/hip_bf16.h>
#include <math.h>

typedef short short8 __attribute__((ext_vector_type(8)));
typedef float f32x16 __attribute__((ext_vector_type(16)));

#define BB 16
#define CC 256
#define HH 64
#define WW 64
#define HWX 4096
#define DD 4
#define KD 9
#define KK 81
#define NSLOT 10

// LDS visibility barrier WITHOUT vmcnt drain (global loads/stores stay in flight)
#define RAW_BAR() do { \
    asm volatile("s_waitcnt lgkmcnt(0)" ::: "memory"); \
    __builtin_amdgcn_s_barrier(); \
} while (0)

__device__ __forceinline__ short bf16c(float x) {
    __hip_bfloat16 h = __float2bfloat16(x);
    return *reinterpret_cast<short*>(&h);
}

// 512B-row layout, 5-bit XOR swizzle (R11-measured: 0 conflicts)
__device__ __forceinline__ int lds_byte(int w, int c) {
    return (w * 512 + c * 2) ^ ((w & 31) << 4);
}

// 16 strided loads: c = c0..c0+15 at w=l (row, c0 wave-uniform)
__device__ __forceinline__ void b_issue16(const float* __restrict__ row,
                                          int c0, int l, float* v) {
    #pragma unroll
    for (int j = 0; j < 16; ++j)
        v[j] = row[(size_t)(c0 + j) * HWX + l];
}

// cvt + 2 swizzled ds_write_b128; returns sumsq partial
__device__ __forceinline__ float b_commit16(const float* v, unsigned short* bufp,
                                            int c0, int l) {
    float ss = 0.f;
    #pragma unroll
    for (int j = 0; j < 16; ++j) ss += v[j] * v[j];
    #pragma unroll
    for (int h = 0; h < 2; ++h) {
        short8 st;
        #pragma unroll
        for (int j = 0; j < 8; ++j) st[j] = bf16c(v[h * 8 + j]);
        *(short8*)((char*)bufp + lds_byte(l, c0 + h * 8)) = st;
    }
    return ss;
}

__global__ __launch_bounds__(512) void corr_mfma(
    const float* __restrict__ fA, const float* __restrict__ fB,
    float* __restrict__ out)
{
    __shared__ __attribute__((aligned(16))) unsigned short buf[2][WW * CC]; // 64 KB
    __shared__ float part[2][8 * WW];   // 4 KB ([1] aliases A partials)
    __shared__ float invA_ls[2][WW];    // 0.5 KB

    const int bid = blockIdx.x;                       // 512 blocks
    const int swzb = (bid & 7) * 64 + (bid >> 3);     // XCD-bijective (512%8==0)
    const int b = swzb >> 5, jr = swzb & 31;
    const int h0 = 2 * jr;

    const int tid = threadIdx.x;
    const int l = tid & 63;
    const int wvu = __builtin_amdgcn_readfirstlane(tid >> 6);  // wave id -> SGPR
    const int g = wvu >> 2;               // group: row h0+g   (uniform)
    const int q = wvu & 3;                // quadrant wave     (uniform)
    const int hg = h0 + g;
    const int ti = q >> 1, tj = q & 1;
    const int ml = l & 31, kg = l >> 5;
    const int m = ti * 32 + ml;           // A row (w)
    const int n = tj * 32 + ml;           // B row (w')

    // ---- hoist slot-0 B loads to kernel start (latency hides under prologue) ----
    const float* fBb = fB + (size_t)b * CC * HWX;
    const int hb0 = h0 - DD;
    const bool b0v = (unsigned)hb0 < HH;
    float v0a[16], v0b[16];
    if (b0v) {
        const float* row0 = fBb + (size_t)hb0 * WW;
        b_issue16(row0, wvu * 32, l, v0a);
        b_issue16(row0, wvu * 32 + 16, l, v0b);
    }

    // ---- A prologue: single pass -> raw-bf16 stage + sumsq ----
    const float* Abase = fA + (size_t)b * CC * HWX + hg * WW;
    {
        float ss = 0.f;
        #pragma unroll
        for (int r = 0; r < 8; ++r) {
            const int c = q * 64 + r * 8;              // uniform
            float v[8]; short8 st;
            #pragma unroll
            for (int j = 0; j < 8; ++j) v[j] = Abase[(size_t)(c + j) * HWX + l];
            #pragma unroll
            for (int j = 0; j < 8; ++j) ss += v[j] * v[j];
            #pragma unroll
            for (int j = 0; j < 8; ++j) st[j] = bf16c(v[j]);
            *(short8*)((char*)buf[g] + lds_byte(l, c)) = st;
        }
        part[1][wvu * 64 + l] = ss;
    }
    __syncthreads();                                   // bar1: A staged
    if (tid < 2 * WW) {
        const int gg = tid >> 6, ll = tid & 63;
        float s = part[1][(gg * 4 + 0) * 64 + ll] + part[1][(gg * 4 + 1) * 64 + ll]
                + part[1][(gg * 4 + 2) * 64 + ll] + part[1][(gg * 4 + 3) * 64 + ll];
        invA_ls[gg][ll] = 1.f / fmaxf(sqrtf(s), 1e-12f);
    }
    short8 afr[16];
    #pragma unroll
    for (int s = 0; s < 16; ++s)
        afr[s] = *(const short8*)((const char*)buf[g] + lds_byte(m, s * 16 + kg * 8));
    __syncthreads();                                   // bar2: invA visible, hoist done
    {   // fold invA[m] into A fragments (register-only)
        const float iam = invA_ls[g][m];
        #pragma unroll
        for (int s = 0; s < 16; ++s) {
            short8 t = afr[s];
            #pragma unroll
            for (int j = 0; j < 8; ++j) {
                union { unsigned u; float f; } uu;
                uu.u = ((unsigned)(unsigned short)t[j]) << 16;
                t[j] = bf16c(uu.f * iam);
            }
            afr[s] = t;
        }
    }
    // commit the pre-issued slot-0 B row (loads have been in flight all prologue)
    if (b0v) {
        float ss = b_commit16(v0a, buf[0], wvu * 32, l);
        ss += b_commit16(v0b, buf[0], wvu * 32 + 16, l);
        part[0][wvu * 64 + l] = ss;
    }
    __syncthreads();                                   // bar3: slot 0 ready

    // ---- slot loop: 1 raw barrier per slot, direct banded out-stores ----
    for (int r = 0; r < NSLOT; ++r) {
        const int cur = r & 1;
        const int hb = h0 - DD + r;
        const bool vcur = (unsigned)hb < HH;
        const bool vnext = (r + 1 < NSLOT) && ((unsigned)(hb + 1) < HH);
        const int dy = r - g;
        const bool dyv = (dy >= 0 && dy < KD);
        const bool comp = dyv && vcur;
        const float* nrow = fBb + (size_t)(hb + 1) * WW;
        float* ob = out + (((size_t)b * KK + dy * KD) * HH + hg) * WW;

        // 1. issue half0 of next row
        float v[16];
        if (vnext) b_issue16(nrow, wvu * 32, l, v);

        // 2. ibn chain issued early (LDS reads + sqrt overlap MFMA), then octet 1
        f32x16 acc;
        float ibn = 0.f;
        if (comp) {
            float sB = 0.f;
            #pragma unroll
            for (int qq = 0; qq < 8; ++qq) sB += part[cur][qq * 64 + n];
            ibn = 1.f / fmaxf(sqrtf(sB), 1e-12f);
            #pragma unroll
            for (int i = 0; i < 16; ++i) acc[i] = 0.f;
            #pragma unroll
            for (int s = 0; s < 8; ++s) {
                short8 bfr = *(const short8*)((const char*)buf[cur] + lds_byte(n, s * 16 + kg * 8));
                acc = __builtin_amdgcn_mfma_f32_32x32x16_bf16(afr[s], bfr, acc, 0, 0, 0);
            }
        }

        // 3. commit half0, issue half1
        float ssn = 0.f;
        if (vnext) {
            ssn = b_commit16(v, buf[cur ^ 1], wvu * 32, l);
            b_issue16(nrow, wvu * 32 + 16, l, v);
        }

        // 4. MFMA octet 2 + direct banded store
        if (comp) {
            #pragma unroll
            for (int s = 8; s < 16; ++s) {
                short8 bfr = *(const short8*)((const char*)buf[cur] + lds_byte(n, s * 16 + kg * 8));
                acc = __builtin_amdgcn_mfma_f32_32x32x16_bf16(afr[s], bfr, acc, 0, 0, 0);
            }
            #pragma unroll
            for (int rr = 0; rr < 16; ++rr) {
                // D layout (m74/m101): col = lane&31 (=w'), row = (rr&3)+8*(rr>>2)+4*kg
                const int w = ti * 32 + (rr & 3) + 8 * (rr >> 2) + 4 * kg;
                const int dx = n - w + 4;
                if (dx >= 0 && dx < KD)
                    ob[(size_t)dx * HWX + w] = acc[rr] * ibn;   // invA folded in afr
            }
            if (q == 3) {      // zero the 20 pad-corner entries of this plane
                int i = -1;
                if (l < 10) i = l;
                else if (l >= 16 && l < 26) i = l - 16;
                if (i >= 0) {
                    const int wz0 = (i < 4) ? 0 : (i < 7) ? 1 : (i < 9) ? 2 : 3;
                    const int dx0 = i - ((wz0 == 0) ? 0 : (wz0 == 1) ? 4 : (wz0 == 2) ? 7 : 9);
                    const int wz = (l < 10) ? wz0 : 63 - wz0;
                    const int dxz = (l < 10) ? dx0 : 8 - dx0;
                    ob[(size_t)dxz * HWX + wz] = 0.f;
                }
            }
        } else if (dyv) {
            // whole dy-plane is zero padding; out is poisoned so must write
            for (int i = q * 64 + l; i < KD * WW; i += 256)
                ob[(size_t)(i >> 6) * HWX + (i & 63)] = 0.f;
        }

        // 5. commit half1, publish sumsq partial
        if (vnext) {
            ssn += b_commit16(v, buf[cur ^ 1], wvu * 32 + 16, l);
            part[cur ^ 1][wvu * 64 + l] = ssn;
        }
        if (r != NSLOT - 1) RAW_BAR();                 // no barrier after last slot
    }
}

extern "C" void kernel_launch(void* const* d_in, const int* in_sizes, int n_in,
                              void* d_out, int out_size, void* d_ws, size_t ws_size,
                              hipStream_t stream) {
    const float* fA = (const float*)d_in[0];
    const float* fB = (const float*)d_in[1];
    float* outp = (float*)d_out;
    corr_mfma<<<dim3(BB * HH / 2), 512, 0, stream>>>(fA, fB, outp);
}

// Round 17
// 60.032 us; speedup vs baseline: 1.9516x; 1.0981x over previous
//
#include <hip/hip_runtime.h>
#include <hip/hip_bf16.h>
#include <math.h>

typedef short short8 __attribute__((ext_vector_type(8)));
typedef float f32x16 __attribute__((ext_vector_type(16)));

#define BB 16
#define CC 256
#define HH 64
#define WW 64
#define HWX 4096
#define DD 4
#define KD 9
#define KK 81
#define NSLOT 10

// LDS visibility barrier WITHOUT vmcnt drain (global loads/stores stay in flight)
#define RAW_BAR() do { \
    asm volatile("s_waitcnt lgkmcnt(0)" ::: "memory"); \
    __builtin_amdgcn_s_barrier(); \
} while (0)

__device__ __forceinline__ short bf16c(float x) {
    __hip_bfloat16 h = __float2bfloat16(x);
    return *reinterpret_cast<short*>(&h);
}

// 512B-row layout, 5-bit XOR swizzle (R11-measured: 0 conflicts)
__device__ __forceinline__ int lds_byte(int w, int c) {
    return (w * 512 + c * 2) ^ ((w & 31) << 4);
}

// 16 strided loads: c = c0..c0+15 at w=l (row, c0 wave-uniform)
__device__ __forceinline__ void b_issue16(const float* __restrict__ row,
                                          int c0, int l, float* v) {
    #pragma unroll
    for (int j = 0; j < 16; ++j)
        v[j] = row[(size_t)(c0 + j) * HWX + l];
}

// cvt + 2 swizzled ds_write_b128; returns sumsq partial
__device__ __forceinline__ float b_commit16(const float* v, unsigned short* bufp,
                                            int c0, int l) {
    float ss = 0.f;
    #pragma unroll
    for (int j = 0; j < 16; ++j) ss += v[j] * v[j];
    #pragma unroll
    for (int h = 0; h < 2; ++h) {
        short8 st;
        #pragma unroll
        for (int j = 0; j < 8; ++j) st[j] = bf16c(v[h * 8 + j]);
        *(short8*)((char*)bufp + lds_byte(l, c0 + h * 8)) = st;
    }
    return ss;
}

__global__ __launch_bounds__(512) void corr_mfma(
    const float* __restrict__ fA, const float* __restrict__ fB,
    float* __restrict__ out)
{
    __shared__ __attribute__((aligned(16))) unsigned short buf[2][WW * CC]; // 64 KB
    __shared__ float part[2][8 * WW];   // 4 KB ([1] aliases A partials)
    __shared__ float invA_ls[2][WW];    // 0.5 KB            -> total ~68.5 KB

    const int bid = blockIdx.x;                       // 512 blocks
    const int swzb = (bid & 7) * 64 + (bid >> 3);     // XCD-bijective (512%8==0)
    const int b = swzb >> 5, jr = swzb & 31;
    const int h0 = 2 * jr;

    const int tid = threadIdx.x;
    const int l = tid & 63;
    const int wvu = __builtin_amdgcn_readfirstlane(tid >> 6);  // wave id -> SGPR
    const int g = wvu >> 2;               // group: row h0+g   (uniform)
    const int q = wvu & 3;                // quadrant wave     (uniform)
    const int hg = h0 + g;
    const int ti = q >> 1, tj = q & 1;
    const int ml = l & 31, kg = l >> 5;
    const int m = ti * 32 + ml;           // A row (w)
    const int n = tj * 32 + ml;           // B row (w')

    // ---- A prologue: single pass -> raw-bf16 stage + sumsq ----
    const float* Abase = fA + (size_t)b * CC * HWX + hg * WW;
    {
        float ss = 0.f;
        #pragma unroll
        for (int r = 0; r < 8; ++r) {
            const int c = q * 64 + r * 8;              // uniform
            float v[8]; short8 st;
            #pragma unroll
            for (int j = 0; j < 8; ++j) v[j] = Abase[(size_t)(c + j) * HWX + l];
            #pragma unroll
            for (int j = 0; j < 8; ++j) ss += v[j] * v[j];
            #pragma unroll
            for (int j = 0; j < 8; ++j) st[j] = bf16c(v[j]);
            *(short8*)((char*)buf[g] + lds_byte(l, c)) = st;
        }
        part[1][wvu * 64 + l] = ss;
    }
    __syncthreads();                                   // bar1: A staged
    if (tid < 2 * WW) {
        const int gg = tid >> 6, ll = tid & 63;
        float s = part[1][(gg * 4 + 0) * 64 + ll] + part[1][(gg * 4 + 1) * 64 + ll]
                + part[1][(gg * 4 + 2) * 64 + ll] + part[1][(gg * 4 + 3) * 64 + ll];
        invA_ls[gg][ll] = 1.f / fmaxf(sqrtf(s), 1e-12f);
    }
    short8 afr[16];
    #pragma unroll
    for (int s = 0; s < 16; ++s)
        afr[s] = *(const short8*)((const char*)buf[g] + lds_byte(m, s * 16 + kg * 8));
    __syncthreads();                                   // bar2: invA visible, hoist done
    {   // fold invA[m] into A fragments (register-only)
        const float iam = invA_ls[g][m];
        #pragma unroll
        for (int s = 0; s < 16; ++s) {
            short8 t = afr[s];
            #pragma unroll
            for (int j = 0; j < 8; ++j) {
                union { unsigned u; float f; } uu;
                uu.u = ((unsigned)(unsigned short)t[j]) << 16;
                t[j] = bf16c(uu.f * iam);
            }
            afr[s] = t;
        }
    }
    // slot-0 B staging into buf[0] (hoist reads completed at bar2)
    const float* fBb = fB + (size_t)b * CC * HWX;
    {
        const int hb0 = h0 - DD;
        if ((unsigned)hb0 < HH) {
            const float* row = fBb + (size_t)hb0 * WW;
            float v[16];
            b_issue16(row, wvu * 32, l, v);
            float ss = b_commit16(v, buf[0], wvu * 32, l);
            b_issue16(row, wvu * 32 + 16, l, v);
            ss += b_commit16(v, buf[0], wvu * 32 + 16, l);
            part[0][wvu * 64 + l] = ss;
        }
    }
    __syncthreads();                                   // bar3: slot 0 ready

    // ---- slot loop: 1 raw barrier per slot, direct banded out-stores ----
    for (int r = 0; r < NSLOT; ++r) {
        const int cur = r & 1;
        const int hb = h0 - DD + r;
        const bool vcur = (unsigned)hb < HH;
        const bool vnext = (r + 1 < NSLOT) && ((unsigned)(hb + 1) < HH);
        const int dy = r - g;
        const bool dyv = (dy >= 0 && dy < KD);
        const bool comp = dyv && vcur;
        const float* nrow = fBb + (size_t)(hb + 1) * WW;
        float* ob = out + (((size_t)b * KK + dy * KD) * HH + hg) * WW;

        // 1. issue half0 of next row
        float v[16];
        if (vnext) b_issue16(nrow, wvu * 32, l, v);

        // 2. MFMA octet 1
        f32x16 acc;
        if (comp) {
            #pragma unroll
            for (int i = 0; i < 16; ++i) acc[i] = 0.f;
            __builtin_amdgcn_s_setprio(1);
            #pragma unroll
            for (int s = 0; s < 8; ++s) {
                short8 bfr = *(const short8*)((const char*)buf[cur] + lds_byte(n, s * 16 + kg * 8));
                acc = __builtin_amdgcn_mfma_f32_32x32x16_bf16(afr[s], bfr, acc, 0, 0, 0);
            }
            __builtin_amdgcn_s_setprio(0);
        }

        // 3. commit half0, issue half1
        float ssn = 0.f;
        if (vnext) {
            ssn = b_commit16(v, buf[cur ^ 1], wvu * 32, l);
            b_issue16(nrow, wvu * 32 + 16, l, v);
        }

        // 4. MFMA octet 2 + direct banded store
        if (comp) {
            __builtin_amdgcn_s_setprio(1);
            #pragma unroll
            for (int s = 8; s < 16; ++s) {
                short8 bfr = *(const short8*)((const char*)buf[cur] + lds_byte(n, s * 16 + kg * 8));
                acc = __builtin_amdgcn_mfma_f32_32x32x16_bf16(afr[s], bfr, acc, 0, 0, 0);
            }
            __builtin_amdgcn_s_setprio(0);
            float sB = 0.f;
            #pragma unroll
            for (int qq = 0; qq < 8; ++qq) sB += part[cur][qq * 64 + n];
            const float ibn = 1.f / fmaxf(sqrtf(sB), 1e-12f);
            #pragma unroll
            for (int rr = 0; rr < 16; ++rr) {
                // D layout (m74/m101): col = lane&31 (=w'), row = (rr&3)+8*(rr>>2)+4*kg
                const int w = ti * 32 + (rr & 3) + 8 * (rr >> 2) + 4 * kg;
                const int dx = n - w + 4;
                if (dx >= 0 && dx < KD)
                    ob[(size_t)dx * HWX + w] = acc[rr] * ibn;   // invA folded in afr
            }
            if (q == 3) {      // zero the 20 pad-corner entries of this plane
                int i = -1;
                if (l < 10) i = l;
                else if (l >= 16 && l < 26) i = l - 16;
                if (i >= 0) {
                    const int wz0 = (i < 4) ? 0 : (i < 7) ? 1 : (i < 9) ? 2 : 3;
                    const int dx0 = i - ((wz0 == 0) ? 0 : (wz0 == 1) ? 4 : (wz0 == 2) ? 7 : 9);
                    const int wz = (l < 10) ? wz0 : 63 - wz0;
                    const int dxz = (l < 10) ? dx0 : 8 - dx0;
                    ob[(size_t)dxz * HWX + wz] = 0.f;
                }
            }
        } else if (dyv) {
            // whole dy-plane is zero padding; out is poisoned so must write
            for (int i = q * 64 + l; i < KD * WW; i += 256)
                ob[(size_t)(i >> 6) * HWX + (i & 63)] = 0.f;
        }

        // 5. commit half1, publish sumsq partial
        if (vnext) {
            ssn += b_commit16(v, buf[cur ^ 1], wvu * 32 + 16, l);
            part[cur ^ 1][wvu * 64 + l] = ssn;
        }
        RAW_BAR();
    }
}

extern "C" void kernel_launch(void* const* d_in, const int* in_sizes, int n_in,
                              void* d_out, int out_size, void* d_ws, size_t ws_size,
                              hipStream_t stream) {
    const float* fA = (const float*)d_in[0];
    const float* fB = (const float*)d_in[1];
    float* outp = (float*)d_out;
    corr_mfma<<<dim3(BB * HH / 2), 512, 0, stream>>>(fA, fB, outp);
}